// Round 1
// baseline (5663.906 us; speedup 1.0000x reference)
//
#include <hip/hip_runtime.h>
#include <hip/hip_bf16.h>

// Binary tree LSTM, fp32 baseline.
// B=512, L=256, INP=300, HID=256, NCLS=5.
// Pipeline:
//   leaf:   pre = emb(131072x300) @ Wleaf(300x768) + b  -> gates -> c0,h0
//   levels: pre = lh @ Wl + rh @ Wr + bb (K=512 total, N=1280) -> gates -> c,h
//   logits: h(rows x 256) @ W_out(256x5) + b_out  -> out[b, off+j, :]
// All fp32, gates fused into GEMM epilogues, c/h ping-pong in d_ws.

#define HID 256
#define NB 512
#define NL 256
#define INP 300

__device__ __forceinline__ float sigf(float x) {
    return 1.0f / (1.0f + __expf(-x));
}
__device__ __forceinline__ float tanh_fast(float x) {
    return 2.0f / (1.0f + __expf(-2.0f * x)) - 1.0f;
}

// ---------------- Leaf kernel: 64 rows x (3 gates x 64 cols) per block ----
__global__ __launch_bounds__(256) void leaf_kernel(
    const float* __restrict__ emb,     // (131072, 300)
    const float* __restrict__ W_leaf,  // (3, 300, 256)
    const float* __restrict__ b_leaf,  // (3, 256)
    float* __restrict__ c0,            // (131072, 256)
    float* __restrict__ h0)            // (131072, 256)
{
    __shared__ float As[16][64];
    __shared__ float Bs[16][192];
    const int rb = blockIdx.x;      // 0..2047
    const int col0 = blockIdx.y * 64;
    const int t = threadIdx.x;
    const int tx = t & 15, ty = t >> 4;
    const int row0 = rb * 64;

    float acc[3][4][4] = {};

    for (int k0 = 0; k0 < INP; k0 += 16) {
        __syncthreads();
        // stage A tile (64 rows x 16 k)
        for (int idx = t; idx < 64 * 16; idx += 256) {
            int rl = idx >> 4, kk = idx & 15;
            int k = k0 + kk;
            As[kk][rl] = (k < INP) ? emb[(size_t)(row0 + rl) * INP + k] : 0.0f;
        }
        // stage B tile (16 k x 3*64 cols)
        for (int idx = t; idx < 16 * 192; idx += 256) {
            int kk = idx / 192, cc = idx % 192;
            int g = cc >> 6, c = cc & 63;
            int k = k0 + kk;
            Bs[kk][cc] = (k < INP)
                ? W_leaf[((size_t)g * INP + k) * HID + col0 + c] : 0.0f;
        }
        __syncthreads();
#pragma unroll
        for (int kk = 0; kk < 16; ++kk) {
            const float4 av = *(const float4*)(&As[kk][ty * 4]);
            const float a_[4] = {av.x, av.y, av.z, av.w};
            float b_[3][4];
#pragma unroll
            for (int g = 0; g < 3; ++g) {
                const float4 bv = *(const float4*)(&Bs[kk][g * 64 + tx * 4]);
                b_[g][0] = bv.x; b_[g][1] = bv.y; b_[g][2] = bv.z; b_[g][3] = bv.w;
            }
#pragma unroll
            for (int g = 0; g < 3; ++g)
#pragma unroll
                for (int i = 0; i < 4; ++i)
#pragma unroll
                    for (int j = 0; j < 4; ++j)
                        acc[g][i][j] = fmaf(a_[i], b_[g][j], acc[g][i][j]);
        }
    }

    // epilogue: gates
    const int row_t = row0 + ty * 4;
    const int col_t = col0 + tx * 4;
#pragma unroll
    for (int i = 0; i < 4; ++i) {
        size_t r = row_t + i;
#pragma unroll
        for (int j = 0; j < 4; ++j) {
            int c = col_t + j;
            float pi = acc[0][i][j] + b_leaf[0 * HID + c];
            float po = acc[1][i][j] + b_leaf[1 * HID + c];
            float pu = acc[2][i][j] + b_leaf[2 * HID + c];
            float ig = sigf(pi);
            float og = sigf(po);
            float ug = tanh_fast(pu);
            float cv = ig * ug;
            float hv = og * sigf(cv);   // NOTE: reference uses sigmoid(c) here
            c0[r * HID + c] = cv;
            h0[r * HID + c] = hv;
        }
    }
}

// ---------------- Level kernel: 64 rows x (5 gates x 64 cols) ------------
__global__ __launch_bounds__(256) void level_kernel(
    const float* __restrict__ h_prev,  // (M*2, 256)
    const float* __restrict__ c_prev,  // (M*2, 256)
    const float* __restrict__ W_nl,    // (10, 256, 256)
    const float* __restrict__ b_nl,    // (10, 256)
    float* __restrict__ c_cur,         // (M, 256)
    float* __restrict__ h_cur,         // (M, 256)
    int log2n)                         // nodes this level = 1<<log2n
{
    __shared__ float As[16][64];
    __shared__ float Bs[16][320];
    const int rb = blockIdx.x;
    const int col0 = blockIdx.y * 64;
    const int t = threadIdx.x;
    const int tx = t & 15, ty = t >> 4;
    const int row0 = rb * 64;
    const int n = 1 << log2n;

    float acc[5][4][4] = {};

    for (int phase = 0; phase < 2; ++phase) {
        for (int k0 = 0; k0 < HID; k0 += 16) {
            __syncthreads();
            // stage A: lh (phase 0) or rh (phase 1) rows
            for (int idx = t; idx < 64 * 16; idx += 256) {
                int rl = idx >> 4, kk = idx & 15;
                int r = row0 + rl;
                int b = r >> log2n, j = r & (n - 1);
                size_t prow = ((size_t)b << (log2n + 1)) + 2 * j + phase;
                As[kk][rl] = h_prev[prow * HID + k0 + kk];
            }
            // stage B: W_nl[2g+phase][k][col]
            for (int idx = t; idx < 16 * 320; idx += 256) {
                int kk = idx / 320, cc = idx % 320;
                int g = cc >> 6, c = cc & 63;
                Bs[kk][cc] =
                    W_nl[((size_t)(2 * g + phase) * HID + k0 + kk) * HID + col0 + c];
            }
            __syncthreads();
#pragma unroll
            for (int kk = 0; kk < 16; ++kk) {
                const float4 av = *(const float4*)(&As[kk][ty * 4]);
                const float a_[4] = {av.x, av.y, av.z, av.w};
                float b_[5][4];
#pragma unroll
                for (int g = 0; g < 5; ++g) {
                    const float4 bv = *(const float4*)(&Bs[kk][g * 64 + tx * 4]);
                    b_[g][0] = bv.x; b_[g][1] = bv.y; b_[g][2] = bv.z; b_[g][3] = bv.w;
                }
#pragma unroll
                for (int g = 0; g < 5; ++g)
#pragma unroll
                    for (int i = 0; i < 4; ++i)
#pragma unroll
                        for (int j = 0; j < 4; ++j)
                            acc[g][i][j] = fmaf(a_[i], b_[g][j], acc[g][i][j]);
            }
        }
    }

    // epilogue
    const int row_t = row0 + ty * 4;
    const int col_t = col0 + tx * 4;
#pragma unroll
    for (int i = 0; i < 4; ++i) {
        int r = row_t + i;
        int b = r >> log2n, j = r & (n - 1);
        size_t lrow = ((size_t)b << (log2n + 1)) + 2 * j;
#pragma unroll
        for (int jj = 0; jj < 4; ++jj) {
            int c = col_t + jj;
            float pin = acc[0][i][jj] + b_nl[0 * HID + c] + b_nl[1 * HID + c];
            float pfl = acc[1][i][jj] + b_nl[2 * HID + c] + b_nl[3 * HID + c];
            float pfr = acc[2][i][jj] + b_nl[4 * HID + c] + b_nl[5 * HID + c];
            float pou = acc[3][i][jj] + b_nl[6 * HID + c] + b_nl[7 * HID + c];
            float pup = acc[4][i][jj] + b_nl[8 * HID + c] + b_nl[9 * HID + c];
            float lc = c_prev[lrow * HID + c];
            float rc = c_prev[(lrow + 1) * HID + c];
            float cv = sigf(pin) * tanh_fast(pup) + sigf(pfl) * lc + sigf(pfr) * rc;
            float hv = sigf(pou) * tanh_fast(cv);
            c_cur[(size_t)r * HID + c] = cv;
            h_cur[(size_t)r * HID + c] = hv;
        }
    }
}

// ---------------- Logits: h(rows,256) @ W_out(256,5) + b_out -------------
// 16 lanes per row, 16 rows per block.
__global__ __launch_bounds__(256) void logits_kernel(
    const float* __restrict__ h,      // (rows, 256)
    const float* __restrict__ W_out,  // (256, 5)
    const float* __restrict__ b_out,  // (5,)
    float* __restrict__ out,          // (512*511*5,)
    int rows, int log2n, int off)
{
    __shared__ float Ws[HID * 5];
    __shared__ float bs[5];
    const int t = threadIdx.x;
    for (int i = t; i < HID * 5; i += 256) Ws[i] = W_out[i];
    if (t < 5) bs[t] = b_out[t];
    __syncthreads();

    const int part = t & 15;
    const int rl = t >> 4;
    const int row = blockIdx.x * 16 + rl;

    float a0 = 0.f, a1 = 0.f, a2 = 0.f, a3 = 0.f, a4 = 0.f;
    if (row < rows) {
#pragma unroll
        for (int i = 0; i < 4; ++i) {
            const float4 hv =
                *(const float4*)(&h[(size_t)row * HID + part * 16 + i * 4]);
            const float hh[4] = {hv.x, hv.y, hv.z, hv.w};
#pragma unroll
            for (int e = 0; e < 4; ++e) {
                int c = part * 16 + i * 4 + e;
                a0 = fmaf(hh[e], Ws[c * 5 + 0], a0);
                a1 = fmaf(hh[e], Ws[c * 5 + 1], a1);
                a2 = fmaf(hh[e], Ws[c * 5 + 2], a2);
                a3 = fmaf(hh[e], Ws[c * 5 + 3], a3);
                a4 = fmaf(hh[e], Ws[c * 5 + 4], a4);
            }
        }
    }
#pragma unroll
    for (int m = 8; m >= 1; m >>= 1) {
        a0 += __shfl_xor(a0, m);
        a1 += __shfl_xor(a1, m);
        a2 += __shfl_xor(a2, m);
        a3 += __shfl_xor(a3, m);
        a4 += __shfl_xor(a4, m);
    }
    if (part == 0 && row < rows) {
        int n = 1 << log2n;
        int b = row >> log2n, j = row & (n - 1);
        size_t o = ((size_t)b * 511 + off + j) * 5;
        out[o + 0] = a0 + bs[0];
        out[o + 1] = a1 + bs[1];
        out[o + 2] = a2 + bs[2];
        out[o + 3] = a3 + bs[3];
        out[o + 4] = a4 + bs[4];
    }
}

extern "C" void kernel_launch(void* const* d_in, const int* in_sizes, int n_in,
                              void* d_out, int out_size, void* d_ws, size_t ws_size,
                              hipStream_t stream) {
    const float* emb    = (const float*)d_in[0];
    const float* W_leaf = (const float*)d_in[1];
    const float* b_leaf = (const float*)d_in[2];
    const float* W_nl   = (const float*)d_in[3];
    const float* b_nl   = (const float*)d_in[4];
    const float* W_out  = (const float*)d_in[5];
    const float* b_out  = (const float*)d_in[6];
    float* out = (float*)d_out;

    // workspace layout (fp32 elements):
    //   cA: 131072*256, hA: 131072*256, cB: 65536*256, hB: 65536*256
    float* cA = (float*)d_ws;
    float* hA = cA + (size_t)131072 * HID;
    float* cB = hA + (size_t)131072 * HID;
    float* hB = cB + (size_t)65536 * HID;

    // leaf level (level 0): 131072 rows
    {
        dim3 grid(131072 / 64, 4);
        leaf_kernel<<<grid, 256, 0, stream>>>(emb, W_leaf, b_leaf, cA, hA);
        logits_kernel<<<131072 / 16, 256, 0, stream>>>(
            hA, W_out, b_out, out, 131072, 8, 0);
    }

    const float* cp = cA;
    const float* hp = hA;
    int off = 256;
    for (int lev = 1; lev <= 8; ++lev) {
        int log2n = 8 - lev;
        int n = 1 << log2n;
        int M = 512 * n;
        float* cd = (lev & 1) ? cB : cA;
        float* hd = (lev & 1) ? hB : hA;
        dim3 grid(M / 64, 4);
        level_kernel<<<grid, 256, 0, stream>>>(hp, cp, W_nl, b_nl, cd, hd, log2n);
        logits_kernel<<<M / 16, 256, 0, stream>>>(hd, W_out, b_out, out, M, log2n, off);
        cp = cd;
        hp = hd;
        off += n;
    }
}

// Round 2
// 698.981 us; speedup vs baseline: 8.1031x; 8.1031x over previous
//
#include <hip/hip_runtime.h>
#include <hip/hip_bf16.h>

// Binary tree LSTM, bf16-MFMA version.
// B=512, L=256, INP=300(pad 320), HID=256, NCLS=5.
//   leaf:  embB(131072x320)bf16 @ BleafT -> 3 gates -> c0(f32), h0(bf16)
//   level: h_prev viewed (M x 512)bf16 @ BlevT(1280x512) -> 5 gates -> c,h
//   logits: h(bf16) @ W_out(f32 256x5) per level
// GEMM: 128 x (NG*64) block tile, BK=64, mfma_f32_16x16x32_bf16,
// global_load_lds(16B) with pre-swizzled source, XOR-swizzled ds_read_b128.

#define HID 256

typedef __attribute__((ext_vector_type(8))) short short8;
typedef __attribute__((ext_vector_type(4))) float f32x4;
typedef __attribute__((ext_vector_type(4))) unsigned short ushort4v;

__device__ __forceinline__ float sigf(float x) { return 1.0f / (1.0f + __expf(-x)); }
__device__ __forceinline__ float tanhf_(float x) { return 2.0f / (1.0f + __expf(-2.0f * x)) - 1.0f; }
__device__ __forceinline__ float bf2f(unsigned short u) {
    union { unsigned int i; float f; } v; v.i = ((unsigned int)u) << 16; return v.f;
}
__device__ __forceinline__ unsigned short f2bf(float f) {
    __hip_bfloat16 b = __float2bfloat16(f);
    return *(unsigned short*)&b;
}
__device__ __forceinline__ void gload_lds16(const void* g, void* l) {
    __builtin_amdgcn_global_load_lds(
        (const __attribute__((address_space(1))) unsigned int*)g,
        (__attribute__((address_space(3))) unsigned int*)l, 16, 0, 0);
}

// ---------------- fused GEMM + gates ----------------
// A: (M x K) bf16 row-major. BT: (4*NG*64 x K) bf16 (column-major view of B).
// grid: (M/128, 4). 256 threads = 4 waves, 2M x 2N.
template <int NG, int K, bool LEAF>
__global__ __launch_bounds__(256, 2) void gemm_gates(
    const unsigned short* __restrict__ A,
    const unsigned short* __restrict__ BT,
    const float* __restrict__ bias,     // (NG x 256)
    const float* __restrict__ cprev,    // (M x 512) f32, level only
    float* __restrict__ cout,           // (M x 256) f32
    unsigned short* __restrict__ hout)  // (M x 256) bf16
{
    constexpr int BN = NG * 64;   // block cols (gate-major)
    constexpr int NK = K / 64;
    constexpr int NBI = NG * 2;   // B stage instrs per wave

    __shared__ char smem[(128 + BN) * 128];
    char* As = smem;                // [128 rows][128 B], swizzled
    char* Bs = smem + 128 * 128;    // [BN cols][128 B], swizzled

    const int t = threadIdx.x;
    const int lane = t & 63;
    const int w = t >> 6;
    const int wm = w >> 1, wn = w & 1;
    const int row0 = blockIdx.x * 128;
    const int cb = blockIdx.y;      // 0..3

    // ---- staging source offsets (pre-swizzled: slot = (lane&7) ^ (lane>>3)) ----
    const int l3 = lane >> 3;
    const unsigned int swsrc = (unsigned int)(((lane & 7) ^ l3) * 16);
    unsigned int a_src[4];
    unsigned int b_src[NBI];
#pragma unroll
    for (int q = 0; q < 4; ++q) {
        int row = (w * 4 + q) * 8 + l3;
        a_src[q] = (unsigned int)(row0 + row) * (K * 2) + swsrc;
    }
#pragma unroll
    for (int q = 0; q < NBI; ++q) {
        int colp = (w * NBI + q) * 8 + l3;
        b_src[q] = (unsigned int)(cb * BN + colp) * (K * 2) + swsrc;
    }

    // ---- ds_read offsets ----
    const int swz0 = ((lane >> 4) ^ (lane & 7)) * 16;
    const int swz1 = (((lane >> 4) + 4) ^ (lane & 7)) * 16;
    const int abase = (wm * 64 + (lane & 15)) * 128;
    const int bbase = (wn * 32 + (lane & 15)) * 128;

    f32x4 acc[4][NG * 2] = {};

    for (int kt = 0; kt < NK; ++kt) {
        const unsigned int k0b = kt * 128;
#pragma unroll
        for (int q = 0; q < 4; ++q)
            gload_lds16((const char*)A + (size_t)(a_src[q] + k0b),
                        As + (w * 4 + q) * 1024);
#pragma unroll
        for (int q = 0; q < NBI; ++q)
            gload_lds16((const char*)BT + (size_t)(b_src[q] + k0b),
                        Bs + (w * NBI + q) * 1024);
        __syncthreads();
#pragma unroll
        for (int ks = 0; ks < 2; ++ks) {
            const int sw = ks ? swz1 : swz0;
            short8 a[4];
#pragma unroll
            for (int mf = 0; mf < 4; ++mf)
                a[mf] = *(const short8*)(As + abase + mf * 2048 + sw);
#pragma unroll
            for (int g = 0; g < NG; ++g) {
                short8 b0 = *(const short8*)(Bs + bbase + g * 8192 + sw);
                short8 b1 = *(const short8*)(Bs + bbase + g * 8192 + 2048 + sw);
#pragma unroll
                for (int mf = 0; mf < 4; ++mf) {
                    acc[mf][g * 2 + 0] = __builtin_amdgcn_mfma_f32_16x16x32_bf16(
                        a[mf], b0, acc[mf][g * 2 + 0], 0, 0, 0);
                    acc[mf][g * 2 + 1] = __builtin_amdgcn_mfma_f32_16x16x32_bf16(
                        a[mf], b1, acc[mf][g * 2 + 1], 0, 0, 0);
                }
            }
        }
        __syncthreads();
    }

    // ---- epilogue: gates ----
    const int cw = cb * 64 + wn * 32;
#pragma unroll
    for (int mf = 0; mf < 4; ++mf) {
#pragma unroll
        for (int j = 0; j < 4; ++j) {
            const int r = row0 + wm * 64 + mf * 16 + ((lane >> 4) << 2) + j;
#pragma unroll
            for (int fc = 0; fc < 2; ++fc) {
                const int c = cw + fc * 16 + (lane & 15);
                if constexpr (LEAF) {
                    float p0 = acc[mf][0 + fc][j] + bias[c];          // i
                    float p1 = acc[mf][2 + fc][j] + bias[256 + c];    // o
                    float p2 = acc[mf][4 + fc][j] + bias[512 + c];    // u
                    float cv = sigf(p0) * tanhf_(p2);
                    float hv = sigf(p1) * sigf(cv);   // reference: o*sig(c)
                    cout[(size_t)r * 256 + c] = cv;
                    hout[(size_t)r * 256 + c] = f2bf(hv);
                } else {
                    float p0 = acc[mf][0 + fc][j] + bias[c];           // inp
                    float p1 = acc[mf][2 + fc][j] + bias[256 + c];     // fol
                    float p2 = acc[mf][4 + fc][j] + bias[512 + c];     // for
                    float p3 = acc[mf][6 + fc][j] + bias[768 + c];     // out
                    float p4 = acc[mf][8 + fc][j] + bias[1024 + c];    // upd
                    float lc = cprev[(size_t)r * 512 + c];
                    float rc = cprev[(size_t)r * 512 + 256 + c];
                    float cv = sigf(p0) * tanhf_(p4) + sigf(p1) * lc + sigf(p2) * rc;
                    float hv = sigf(p3) * tanhf_(cv);
                    cout[(size_t)r * 256 + c] = cv;
                    hout[(size_t)r * 256 + c] = f2bf(hv);
                }
            }
        }
    }
}

// ---------------- weight prep ----------------
__global__ __launch_bounds__(256) void prep_weights(
    const float* __restrict__ W_leaf, const float* __restrict__ W_nl,
    const float* __restrict__ b_nl,
    unsigned short* __restrict__ BleafT, unsigned short* __restrict__ BlevT,
    float* __restrict__ bb)
{
    const int T1 = 768 * 320, T2 = 1280 * 512, T3 = 5 * 256;
    for (int idx = blockIdx.x * 256 + threadIdx.x; idx < T1 + T2 + T3;
         idx += gridDim.x * 256) {
        if (idx < T1) {
            int colp = idx / 320, k = idx % 320;
            int cbv = colp / 192, rem = colp % 192;
            int g = rem >> 6, cl = rem & 63;
            int c = cbv * 64 + cl;
            float v = (k < 300) ? W_leaf[((size_t)g * 300 + k) * 256 + c] : 0.0f;
            BleafT[(size_t)colp * 320 + k] = f2bf(v);
        } else if (idx < T1 + T2) {
            int i2 = idx - T1;
            int colp = i2 / 512, k = i2 % 512;
            int cbv = colp / 320, rem = colp % 320;
            int g = rem >> 6, cl = rem & 63;
            int c = cbv * 64 + cl;
            float v = W_nl[((size_t)(2 * g + (k >= 256)) * 256 + (k & 255)) * 256 + c];
            BlevT[(size_t)colp * 512 + k] = f2bf(v);
        } else {
            int i3 = idx - T1 - T2;  // g*256 + c
            bb[i3] = b_nl[(size_t)(i3 >> 8) * 512 + (i3 & 255)] +
                     b_nl[(size_t)(i3 >> 8) * 512 + 256 + (i3 & 255)];
        }
    }
}

// ---------------- emb -> bf16, pad 300 -> 320 ----------------
__global__ __launch_bounds__(256) void emb_to_bf16(
    const float* __restrict__ emb, unsigned short* __restrict__ embB)
{
    const int total = 131072 * 80;  // quads of 4
    for (int idx = blockIdx.x * 256 + threadIdx.x; idx < total;
         idx += gridDim.x * 256) {
        int r = idx / 80, q = idx % 80;
        ushort4v o;
        if (q < 75) {
            const float4 v = *(const float4*)(emb + (size_t)r * 300 + q * 4);
            o.x = f2bf(v.x); o.y = f2bf(v.y); o.z = f2bf(v.z); o.w = f2bf(v.w);
        } else {
            o.x = 0; o.y = 0; o.z = 0; o.w = 0;
        }
        *(ushort4v*)(embB + (size_t)r * 320 + q * 4) = o;
    }
}

// ---------------- logits: h(bf16) @ W_out + b_out ----------------
__global__ __launch_bounds__(256) void logits_bf16(
    const unsigned short* __restrict__ h, const float* __restrict__ W_out,
    const float* __restrict__ b_out, float* __restrict__ out,
    int rows, int log2n, int off)
{
    __shared__ float Ws[HID * 5];
    __shared__ float bs[5];
    const int t = threadIdx.x;
    for (int i = t; i < HID * 5; i += 256) Ws[i] = W_out[i];
    if (t < 5) bs[t] = b_out[t];
    __syncthreads();

    const int part = t & 15;
    const int rl = t >> 4;
    const int row = blockIdx.x * 16 + rl;

    float a0 = 0.f, a1 = 0.f, a2 = 0.f, a3 = 0.f, a4 = 0.f;
    if (row < rows) {
#pragma unroll
        for (int i = 0; i < 2; ++i) {
            short8 hv = *(const short8*)(h + (size_t)row * HID + part * 16 + i * 8);
#pragma unroll
            for (int e = 0; e < 8; ++e) {
                float f = bf2f((unsigned short)hv[e]);
                int c = part * 16 + i * 8 + e;
                a0 = fmaf(f, Ws[c * 5 + 0], a0);
                a1 = fmaf(f, Ws[c * 5 + 1], a1);
                a2 = fmaf(f, Ws[c * 5 + 2], a2);
                a3 = fmaf(f, Ws[c * 5 + 3], a3);
                a4 = fmaf(f, Ws[c * 5 + 4], a4);
            }
        }
    }
#pragma unroll
    for (int m = 8; m >= 1; m >>= 1) {
        a0 += __shfl_xor(a0, m);
        a1 += __shfl_xor(a1, m);
        a2 += __shfl_xor(a2, m);
        a3 += __shfl_xor(a3, m);
        a4 += __shfl_xor(a4, m);
    }
    if (part == 0 && row < rows) {
        int n = 1 << log2n;
        int b = row >> log2n, j = row & (n - 1);
        size_t o = ((size_t)b * 511 + off + j) * 5;
        out[o + 0] = a0 + bs[0];
        out[o + 1] = a1 + bs[1];
        out[o + 2] = a2 + bs[2];
        out[o + 3] = a3 + bs[3];
        out[o + 4] = a4 + bs[4];
    }
}

extern "C" void kernel_launch(void* const* d_in, const int* in_sizes, int n_in,
                              void* d_out, int out_size, void* d_ws, size_t ws_size,
                              hipStream_t stream) {
    const float* emb    = (const float*)d_in[0];
    const float* W_leaf = (const float*)d_in[1];
    const float* b_leaf = (const float*)d_in[2];
    const float* W_nl   = (const float*)d_in[3];
    const float* b_nl   = (const float*)d_in[4];
    const float* W_out  = (const float*)d_in[5];
    const float* b_out  = (const float*)d_in[6];
    float* out = (float*)d_out;

    // workspace layout (bytes)
    char* ws = (char*)d_ws;
    unsigned short* embB   = (unsigned short*)(ws);              // 131072*320*2 = 83,886,080
    unsigned short* BleafT = (unsigned short*)(ws + 83886080);   // 768*320*2    =    491,520
    unsigned short* BlevT  = (unsigned short*)(ws + 84377600);   // 1280*512*2   =  1,310,720
    float*          bb     = (float*)(ws + 85688320);            // 5*256*4      =      5,120
    float*          cA     = (float*)(ws + 85693440);            // 131072*256*4 = 134,217,728
    unsigned short* hA     = (unsigned short*)(ws + 219911168);  // 131072*256*2 =  67,108,864
    float*          cB     = (float*)(ws + 287020032);           // 65536*256*4  =  67,108,864
    unsigned short* hB     = (unsigned short*)(ws + 354128896);  // 65536*256*2  =  33,554,432

    prep_weights<<<1024, 256, 0, stream>>>(W_leaf, W_nl, b_nl, BleafT, BlevT, bb);
    emb_to_bf16<<<2048, 256, 0, stream>>>(emb, embB);

    // leaf: M = 131072, K = 320, NG = 3
    gemm_gates<3, 320, true><<<dim3(1024, 4), 256, 0, stream>>>(
        embB, BleafT, b_leaf, nullptr, cA, hA);
    logits_bf16<<<131072 / 16, 256, 0, stream>>>(hA, W_out, b_out, out, 131072, 8, 0);

    const unsigned short* hp = hA;
    const float* cp = cA;
    int off = 256;
    for (int lev = 1; lev <= 8; ++lev) {
        int log2n = 8 - lev;
        int n = 1 << log2n;
        int M = 512 * n;
        float* cd = (lev & 1) ? cB : cA;
        unsigned short* hd = (lev & 1) ? hB : hA;
        gemm_gates<5, 512, false><<<dim3(M / 128, 4), 256, 0, stream>>>(
            hp, BlevT, bb, cp, cd, hd);
        logits_bf16<<<(M + 15) / 16, 256, 0, stream>>>(hd, W_out, b_out, out, M, log2n, off);
        cp = cd;
        hp = hd;
        off += n;
    }
}

// Round 4
// 667.509 us; speedup vs baseline: 8.4851x; 1.0471x over previous
//
#include <hip/hip_runtime.h>
#include <hip/hip_bf16.h>

// Binary tree LSTM, bf16-MFMA, fully fused version.
// B=512, L=256, INP=300, HID=256, NCLS=5.
//   prep:  pack weights to bf16 B^T panels, sum biases, fill out with b_out
//   leaf:  emb(f32, reg-staged->bf16 LDS) @ BleafT -> 3 gates -> c0,h0 + logits
//   level: h_prev (M x 512 bf16) @ BlevT -> 5 gates -> c,h + logits
// Logits fused: per-block 64-col partial dot, atomicAdd into out.
// GEMM: 128 x (NG*64) tile, BK=64, mfma_f32_16x16x32_bf16,
// global_load_lds(16B) pre-swizzled source, XOR-swizzled ds_read_b128.

#define HID 256

typedef __attribute__((ext_vector_type(8))) short short8;
typedef __attribute__((ext_vector_type(4))) float f32x4;

__device__ __forceinline__ float sigf(float x) { return 1.0f / (1.0f + __expf(-x)); }
__device__ __forceinline__ float tanhf_(float x) { return 2.0f / (1.0f + __expf(-2.0f * x)) - 1.0f; }
__device__ __forceinline__ unsigned short f2bf(float f) {
    __hip_bfloat16 b = __float2bfloat16(f);
    return *(unsigned short*)&b;
}
__device__ __forceinline__ void gload_lds16(const void* g, void* l) {
    __builtin_amdgcn_global_load_lds(
        (const __attribute__((address_space(1))) unsigned int*)g,
        (__attribute__((address_space(3))) unsigned int*)l, 16, 0, 0);
}

// ---------------- fused GEMM + gates + logits ----------------
// LEAF: Av = emb (f32, row stride 300), reg-staged to bf16 LDS.
// else: Av = h_prev viewed (M x 512) bf16, global_load_lds staged.
// BT: (4*NG*64 x K) bf16 column-major-of-B, gate-major 64-col blocks, padded.
// grid: (M/128, 4). 256 threads = 4 waves (2M x 2N).
template <int NG, int K, bool LEAF>
__global__ __launch_bounds__(256, 2) void gemm_gates(
    const void* __restrict__ Av,
    const unsigned short* __restrict__ BT,
    const float* __restrict__ bias,     // (NG x 256) effective bias
    const float* __restrict__ cprev,    // (M x 512) f32, level only
    float* __restrict__ cout,           // (M x 256) f32
    unsigned short* __restrict__ hout,  // (M x 256) bf16
    const float* __restrict__ W_out,    // (256, 5) f32
    float* __restrict__ out,            // logits, pre-filled with b_out
    int log2n, int off)
{
    constexpr int BN = NG * 64;   // block cols (gate-major)
    constexpr int NK = K / 64;
    constexpr int NBI = NG * 2;   // B stage instrs per wave

    __shared__ char smem[(128 + BN) * 128];  // leaf 40960, level 57344
    char* As = smem;                // [128 rows][128 B] bf16, swizzled
    char* Bs = smem + 128 * 128;    // [BN cols][128 B] bf16, swizzled

    const int t = threadIdx.x;
    const int lane = t & 63;
    const int w = t >> 6;
    const int wm = w >> 1, wn = w & 1;
    const int row0 = blockIdx.x * 128;
    const int cb = blockIdx.y;      // 0..3

    // ---- staging source offsets (pre-swizzled: slot ^= row&7) ----
    const int l3 = lane >> 3;
    const unsigned int swsrc = (unsigned int)(((lane & 7) ^ l3) * 16);
    unsigned int a_src[4];
    unsigned int b_src[NBI];
    if constexpr (!LEAF) {
#pragma unroll
        for (int q = 0; q < 4; ++q) {
            int row = (w * 4 + q) * 8 + l3;
            a_src[q] = (unsigned int)(row0 + row) * (K * 2) + swsrc;
        }
    }
#pragma unroll
    for (int q = 0; q < NBI; ++q) {
        int colp = (w * NBI + q) * 8 + l3;
        b_src[q] = (unsigned int)(cb * BN + colp) * (K * 2) + swsrc;
    }

    // ---- ds_read offsets ----
    const int swz0 = ((lane >> 4) ^ (lane & 7)) * 16;
    const int swz1 = (((lane >> 4) + 4) ^ (lane & 7)) * 16;
    const int abase = (wm * 64 + (lane & 15)) * 128;
    const int bbase = (wn * 32 + (lane & 15)) * 128;

    f32x4 acc[4][NG * 2] = {};

    for (int kt = 0; kt < NK; ++kt) {
        if constexpr (LEAF) {
            // reg-stage A: fp32 emb -> bf16 swizzled LDS (row stride 300 f32)
            const float* emb = (const float*)Av;
#pragma unroll
            for (int u = 0; u < 4; ++u) {
                int task = u * 256 + t;          // 0..1023
                int rl = task >> 3, s = task & 7;
                int kb = kt * 64 + s * 8;
                float4 v1 = make_float4(0.f, 0.f, 0.f, 0.f);
                float4 v2 = make_float4(0.f, 0.f, 0.f, 0.f);
                const float* src = emb + (size_t)(row0 + rl) * 300 + kb;
                if (kb <= 296) v1 = *(const float4*)src;
                if (kb <= 292) v2 = *(const float4*)(src + 4);
                short8 o;
                o[0] = (short)f2bf(v1.x); o[1] = (short)f2bf(v1.y);
                o[2] = (short)f2bf(v1.z); o[3] = (short)f2bf(v1.w);
                o[4] = (short)f2bf(v2.x); o[5] = (short)f2bf(v2.y);
                o[6] = (short)f2bf(v2.z); o[7] = (short)f2bf(v2.w);
                *(short8*)(As + rl * 128 + ((s ^ (rl & 7)) * 16)) = o;
            }
        } else {
            const unsigned int k0b = kt * 128;
#pragma unroll
            for (int q = 0; q < 4; ++q)
                gload_lds16((const char*)Av + (size_t)(a_src[q] + k0b),
                            As + (w * 4 + q) * 1024);
        }
        {
            const unsigned int k0b = kt * 128;
#pragma unroll
            for (int q = 0; q < NBI; ++q)
                gload_lds16((const char*)BT + (size_t)(b_src[q] + k0b),
                            Bs + (w * NBI + q) * 1024);
        }
        __syncthreads();
#pragma unroll
        for (int ks = 0; ks < 2; ++ks) {
            const int sw = ks ? swz1 : swz0;
            short8 a[4];
#pragma unroll
            for (int mf = 0; mf < 4; ++mf)
                a[mf] = *(const short8*)(As + abase + mf * 2048 + sw);
#pragma unroll
            for (int g = 0; g < NG; ++g) {
                short8 b0 = *(const short8*)(Bs + bbase + g * 8192 + sw);
                short8 b1 = *(const short8*)(Bs + bbase + g * 8192 + 2048 + sw);
#pragma unroll
                for (int mf = 0; mf < 4; ++mf) {
                    acc[mf][g * 2 + 0] = __builtin_amdgcn_mfma_f32_16x16x32_bf16(
                        a[mf], b0, acc[mf][g * 2 + 0], 0, 0, 0);
                    acc[mf][g * 2 + 1] = __builtin_amdgcn_mfma_f32_16x16x32_bf16(
                        a[mf], b1, acc[mf][g * 2 + 1], 0, 0, 0);
                }
            }
        }
        __syncthreads();
    }

    // ---- epilogue: gates + h stash for logits ----
    float* hs = (float*)smem;                    // [128][65]
    float* Ws = (float*)(smem + 128 * 65 * 4);   // [64*5] = 320 entries
    for (int i = t; i < 320; i += 256) Ws[i] = W_out[cb * 320 + i];  // FIX: cover all 320

#pragma unroll
    for (int mf = 0; mf < 4; ++mf) {
#pragma unroll
        for (int j = 0; j < 4; ++j) {
            const int rl = wm * 64 + mf * 16 + ((lane >> 4) << 2) + j;
            const int r = row0 + rl;
#pragma unroll
            for (int fc = 0; fc < 2; ++fc) {
                const int cl = wn * 32 + fc * 16 + (lane & 15);
                const int c = cb * 64 + cl;
                float cv, hv;
                if constexpr (LEAF) {
                    float p0 = acc[mf][0 + fc][j] + bias[c];          // i
                    float p1 = acc[mf][2 + fc][j] + bias[256 + c];    // o
                    float p2 = acc[mf][4 + fc][j] + bias[512 + c];    // u
                    cv = sigf(p0) * tanhf_(p2);
                    hv = sigf(p1) * sigf(cv);   // reference: o * sig(c)
                } else {
                    float p0 = acc[mf][0 + fc][j] + bias[c];           // inp
                    float p1 = acc[mf][2 + fc][j] + bias[256 + c];     // fol
                    float p2 = acc[mf][4 + fc][j] + bias[512 + c];     // for
                    float p3 = acc[mf][6 + fc][j] + bias[768 + c];     // out
                    float p4 = acc[mf][8 + fc][j] + bias[1024 + c];    // upd
                    float lc = cprev[(size_t)r * 512 + c];
                    float rc = cprev[(size_t)r * 512 + 256 + c];
                    cv = sigf(p0) * tanhf_(p4) + sigf(p1) * lc + sigf(p2) * rc;
                    hv = sigf(p3) * tanhf_(cv);
                }
                cout[(size_t)r * 256 + c] = cv;
                hout[(size_t)r * 256 + c] = f2bf(hv);
                hs[rl * 65 + cl] = hv;
            }
        }
    }
    __syncthreads();

    // ---- fused logits: 64-col partial dot + atomicAdd ----
    const int nmask = (1 << log2n) - 1;
    for (int idx = t; idx < 128 * 5; idx += 256) {
        int rl = idx / 5, cls = idx - rl * 5;
        float s = 0.f;
#pragma unroll
        for (int c2 = 0; c2 < 64; ++c2)
            s = fmaf(hs[rl * 65 + c2], Ws[c2 * 5 + cls], s);
        int rg = row0 + rl;
        int b = rg >> log2n, jj = rg & nmask;
        atomicAdd(out + ((size_t)b * 511 + off + jj) * 5 + cls, s);
    }
}

// ---------------- weight prep + out init ----------------
__global__ __launch_bounds__(256) void prep_weights(
    const float* __restrict__ W_leaf, const float* __restrict__ W_nl,
    const float* __restrict__ b_nl, const float* __restrict__ b_out,
    unsigned short* __restrict__ BleafT, unsigned short* __restrict__ BlevT,
    float* __restrict__ bb, float* __restrict__ out)
{
    const int T1 = 768 * 320, T2 = 1280 * 512, T3 = 5 * 256, T4 = 261632 * 5;
    for (int idx = blockIdx.x * 256 + threadIdx.x; idx < T1 + T2 + T3 + T4;
         idx += gridDim.x * 256) {
        if (idx < T1) {
            int colp = idx / 320, k = idx % 320;
            int cbv = colp / 192, rem = colp % 192;
            int g = rem >> 6, cl = rem & 63;
            int c = cbv * 64 + cl;
            float v = (k < 300) ? W_leaf[((size_t)g * 300 + k) * 256 + c] : 0.0f;
            BleafT[(size_t)colp * 320 + k] = f2bf(v);
        } else if (idx < T1 + T2) {
            int i2 = idx - T1;
            int colp = i2 / 512, k = i2 % 512;
            int cbv = colp / 320, rem = colp % 320;
            int g = rem >> 6, cl = rem & 63;
            int c = cbv * 64 + cl;
            float v = W_nl[((size_t)(2 * g + (k >= 256)) * 256 + (k & 255)) * 256 + c];
            BlevT[(size_t)colp * 512 + k] = f2bf(v);
        } else if (idx < T1 + T2 + T3) {
            int i3 = idx - T1 - T2;  // g*256 + c
            bb[i3] = b_nl[(size_t)(i3 >> 8) * 512 + (i3 & 255)] +
                     b_nl[(size_t)(i3 >> 8) * 512 + 256 + (i3 & 255)];
        } else {
            int i4 = idx - T1 - T2 - T3;
            out[i4] = b_out[i4 % 5];
        }
    }
}

extern "C" void kernel_launch(void* const* d_in, const int* in_sizes, int n_in,
                              void* d_out, int out_size, void* d_ws, size_t ws_size,
                              hipStream_t stream) {
    const float* emb    = (const float*)d_in[0];
    const float* W_leaf = (const float*)d_in[1];
    const float* b_leaf = (const float*)d_in[2];
    const float* W_nl   = (const float*)d_in[3];
    const float* b_nl   = (const float*)d_in[4];
    const float* W_out  = (const float*)d_in[5];
    const float* b_out  = (const float*)d_in[6];
    float* out = (float*)d_out;

    // workspace layout (bytes)
    char* ws = (char*)d_ws;
    unsigned short* BleafT = (unsigned short*)(ws);              // 768*320*2    =    491,520
    unsigned short* BlevT  = (unsigned short*)(ws + 491520);     // 1280*512*2   =  1,310,720
    float*          bb     = (float*)(ws + 1802240);             // 5*256*4      =      5,120
    float*          cA     = (float*)(ws + 1807360);             // 131072*256*4 = 134,217,728
    unsigned short* hA     = (unsigned short*)(ws + 136025088);  // 131072*256*2 =  67,108,864
    float*          cB     = (float*)(ws + 203133952);           // 65536*256*4  =  67,108,864
    unsigned short* hB     = (unsigned short*)(ws + 270242816);  // 65536*256*2  =  33,554,432

    prep_weights<<<2048, 256, 0, stream>>>(W_leaf, W_nl, b_nl, b_out,
                                           BleafT, BlevT, bb, out);

    // leaf: M = 131072, K = 320, NG = 3 (+ fused logits, log2n=8, off=0)
    gemm_gates<3, 320, true><<<dim3(1024, 4), 256, 0, stream>>>(
        emb, BleafT, b_leaf, nullptr, cA, hA, W_out, out, 8, 0);

    const unsigned short* hp = hA;
    const float* cp = cA;
    int off = 256;
    for (int lev = 1; lev <= 8; ++lev) {
        int log2n = 8 - lev;
        int n = 1 << log2n;
        int M = 512 * n;
        float* cd = (lev & 1) ? cB : cA;
        unsigned short* hd = (lev & 1) ? hB : hA;
        gemm_gates<5, 512, false><<<dim3(M / 128, 4), 256, 0, stream>>>(
            hp, BlevT, bb, cp, cd, hd, W_out, out, log2n, off);
        cp = cd;
        hp = hd;
        off += n;
    }
}

// Round 5
// 554.859 us; speedup vs baseline: 10.2078x; 1.2030x over previous
//
#include <hip/hip_runtime.h>
#include <hip/hip_bf16.h>

// Binary tree LSTM, bf16-MFMA, fused logits, rcp-based activations.
// B=512, L=256, INP=300(pad 320), HID=256, NCLS=5.
//   prep:  pack weights to bf16 B^T panels, sum biases, fill out with b_out
//   emb:   fp32 emb -> bf16 embB (padded to 320)
//   leaf:  embB(131072x320) @ BleafT -> 3 gates -> c0,h0 + logits
//   level: h_prev (M x 512 bf16) @ BlevT -> 5 gates -> c,h + logits
// GEMM: 128 x (NG*64) tile, BK=64, mfma_f32_16x16x32_bf16,
// global_load_lds(16B) pre-swizzled source, XOR-swizzled ds_read_b128.
// Logits fused: per-block 64-col partial dot, atomicAdd into out.

#define HID 256

typedef __attribute__((ext_vector_type(8))) short short8;
typedef __attribute__((ext_vector_type(4))) float f32x4;
typedef __attribute__((ext_vector_type(4))) unsigned short ushort4v;

__device__ __forceinline__ float rcpf(float x) { return __builtin_amdgcn_rcpf(x); }
__device__ __forceinline__ float sigf(float x) { return rcpf(1.0f + __expf(-x)); }
__device__ __forceinline__ float tanhf_(float x) { return 2.0f * rcpf(1.0f + __expf(-2.0f * x)) - 1.0f; }
__device__ __forceinline__ unsigned short f2bf(float f) {
    __hip_bfloat16 b = __float2bfloat16(f);
    return *(unsigned short*)&b;
}
__device__ __forceinline__ void gload_lds16(const void* g, void* l) {
    __builtin_amdgcn_global_load_lds(
        (const __attribute__((address_space(1))) unsigned int*)g,
        (__attribute__((address_space(3))) unsigned int*)l, 16, 0, 0);
}

// ---------------- fused GEMM + gates + logits ----------------
// A: (M x K) bf16 row-major. BT: (4*NG*64 x K) bf16 column-major-of-B,
// gate-major 64-col blocks. grid: (M/128, 4). 256 threads = 4 waves (2Mx2N).
template <int NG, int K, bool LEAF>
__global__ __launch_bounds__(256, 2) void gemm_gates(
    const unsigned short* __restrict__ A,
    const unsigned short* __restrict__ BT,
    const float* __restrict__ bias,     // (NG x 256) effective bias
    const float* __restrict__ cprev,    // (M x 512) f32, level only
    float* __restrict__ cout,           // (M x 256) f32
    unsigned short* __restrict__ hout,  // (M x 256) bf16
    const float* __restrict__ W_out,    // (256, 5) f32
    float* __restrict__ out,            // logits, pre-filled with b_out
    int log2n, int off)
{
    constexpr int BN = NG * 64;   // block cols (gate-major)
    constexpr int NK = K / 64;
    constexpr int NBI = NG * 2;   // B stage instrs per wave

    __shared__ char smem[(128 + BN) * 128];  // leaf 40960, level 57344
    char* As = smem;                // [128 rows][128 B] bf16, swizzled
    char* Bs = smem + 128 * 128;    // [BN cols][128 B] bf16, swizzled

    const int t = threadIdx.x;
    const int lane = t & 63;
    const int w = t >> 6;
    const int wm = w >> 1, wn = w & 1;
    const int row0 = blockIdx.x * 128;
    const int cb = blockIdx.y;      // 0..3

    // ---- staging source offsets (pre-swizzled: slot ^= row&7) ----
    const int l3 = lane >> 3;
    const unsigned int swsrc = (unsigned int)(((lane & 7) ^ l3) * 16);
    unsigned int a_src[4];
    unsigned int b_src[NBI];
#pragma unroll
    for (int q = 0; q < 4; ++q) {
        int row = (w * 4 + q) * 8 + l3;
        a_src[q] = (unsigned int)(row0 + row) * (K * 2) + swsrc;
    }
#pragma unroll
    for (int q = 0; q < NBI; ++q) {
        int colp = (w * NBI + q) * 8 + l3;
        b_src[q] = (unsigned int)(cb * BN + colp) * (K * 2) + swsrc;
    }

    // ---- ds_read offsets ----
    const int swz0 = ((lane >> 4) ^ (lane & 7)) * 16;
    const int swz1 = (((lane >> 4) + 4) ^ (lane & 7)) * 16;
    const int abase = (wm * 64 + (lane & 15)) * 128;
    const int bbase = (wn * 32 + (lane & 15)) * 128;

    f32x4 acc[4][NG * 2] = {};

    for (int kt = 0; kt < NK; ++kt) {
        const unsigned int k0b = kt * 128;
#pragma unroll
        for (int q = 0; q < 4; ++q)
            gload_lds16((const char*)A + (size_t)(a_src[q] + k0b),
                        As + (w * 4 + q) * 1024);
#pragma unroll
        for (int q = 0; q < NBI; ++q)
            gload_lds16((const char*)BT + (size_t)(b_src[q] + k0b),
                        Bs + (w * NBI + q) * 1024);
        __syncthreads();
#pragma unroll
        for (int ks = 0; ks < 2; ++ks) {
            const int sw = ks ? swz1 : swz0;
            short8 a[4];
#pragma unroll
            for (int mf = 0; mf < 4; ++mf)
                a[mf] = *(const short8*)(As + abase + mf * 2048 + sw);
#pragma unroll
            for (int g = 0; g < NG; ++g) {
                short8 b0 = *(const short8*)(Bs + bbase + g * 8192 + sw);
                short8 b1 = *(const short8*)(Bs + bbase + g * 8192 + 2048 + sw);
#pragma unroll
                for (int mf = 0; mf < 4; ++mf) {
                    acc[mf][g * 2 + 0] = __builtin_amdgcn_mfma_f32_16x16x32_bf16(
                        a[mf], b0, acc[mf][g * 2 + 0], 0, 0, 0);
                    acc[mf][g * 2 + 1] = __builtin_amdgcn_mfma_f32_16x16x32_bf16(
                        a[mf], b1, acc[mf][g * 2 + 1], 0, 0, 0);
                }
            }
        }
        __syncthreads();
    }

    // ---- epilogue: gates + h stash for logits ----
    float* hs = (float*)smem;                    // [128][65]
    float* Ws = (float*)(smem + 128 * 65 * 4);   // [64*5] = 320 entries
    for (int i = t; i < 320; i += 256) Ws[i] = W_out[cb * 320 + i];

#pragma unroll
    for (int mf = 0; mf < 4; ++mf) {
#pragma unroll
        for (int j = 0; j < 4; ++j) {
            const int rl = wm * 64 + mf * 16 + ((lane >> 4) << 2) + j;
            const int r = row0 + rl;
#pragma unroll
            for (int fc = 0; fc < 2; ++fc) {
                const int cl = wn * 32 + fc * 16 + (lane & 15);
                const int c = cb * 64 + cl;
                float cv, hv;
                if constexpr (LEAF) {
                    float p0 = acc[mf][0 + fc][j] + bias[c];          // i
                    float p1 = acc[mf][2 + fc][j] + bias[256 + c];    // o
                    float p2 = acc[mf][4 + fc][j] + bias[512 + c];    // u
                    cv = sigf(p0) * tanhf_(p2);
                    hv = sigf(p1) * sigf(cv);   // reference: o * sig(c)
                } else {
                    float p0 = acc[mf][0 + fc][j] + bias[c];           // inp
                    float p1 = acc[mf][2 + fc][j] + bias[256 + c];     // fol
                    float p2 = acc[mf][4 + fc][j] + bias[512 + c];     // for
                    float p3 = acc[mf][6 + fc][j] + bias[768 + c];     // out
                    float p4 = acc[mf][8 + fc][j] + bias[1024 + c];    // upd
                    float lc = cprev[(size_t)r * 512 + c];
                    float rc = cprev[(size_t)r * 512 + 256 + c];
                    cv = sigf(p0) * tanhf_(p4) + sigf(p1) * lc + sigf(p2) * rc;
                    hv = sigf(p3) * tanhf_(cv);
                }
                cout[(size_t)r * 256 + c] = cv;
                hout[(size_t)r * 256 + c] = f2bf(hv);
                hs[rl * 65 + cl] = hv;
            }
        }
    }
    __syncthreads();

    // ---- fused logits: 64-col partial dot + atomicAdd ----
    const int nmask = (1 << log2n) - 1;
    for (int idx = t; idx < 128 * 5; idx += 256) {
        int rl = idx / 5, cls = idx - rl * 5;
        float s = 0.f;
#pragma unroll
        for (int c2 = 0; c2 < 64; ++c2)
            s = fmaf(hs[rl * 65 + c2], Ws[c2 * 5 + cls], s);
        int rg = row0 + rl;
        int b = rg >> log2n, jj = rg & nmask;
        atomicAdd(out + ((size_t)b * 511 + off + jj) * 5 + cls, s);
    }
}

// ---------------- weight prep + out init ----------------
__global__ __launch_bounds__(256) void prep_weights(
    const float* __restrict__ W_leaf, const float* __restrict__ W_nl,
    const float* __restrict__ b_nl, const float* __restrict__ b_out,
    unsigned short* __restrict__ BleafT, unsigned short* __restrict__ BlevT,
    float* __restrict__ bb, float* __restrict__ out)
{
    const int T1 = 768 * 320, T2 = 1280 * 512, T3 = 5 * 256, T4 = 261632 * 5;
    for (int idx = blockIdx.x * 256 + threadIdx.x; idx < T1 + T2 + T3 + T4;
         idx += gridDim.x * 256) {
        if (idx < T1) {
            int colp = idx / 320, k = idx % 320;
            int cbv = colp / 192, rem = colp % 192;
            int g = rem >> 6, cl = rem & 63;
            int c = cbv * 64 + cl;
            float v = (k < 300) ? W_leaf[((size_t)g * 300 + k) * 256 + c] : 0.0f;
            BleafT[(size_t)colp * 320 + k] = f2bf(v);
        } else if (idx < T1 + T2) {
            int i2 = idx - T1;
            int colp = i2 / 512, k = i2 % 512;
            int cbv = colp / 320, rem = colp % 320;
            int g = rem >> 6, cl = rem & 63;
            int c = cbv * 64 + cl;
            float v = W_nl[((size_t)(2 * g + (k >= 256)) * 256 + (k & 255)) * 256 + c];
            BlevT[(size_t)colp * 512 + k] = f2bf(v);
        } else if (idx < T1 + T2 + T3) {
            int i3 = idx - T1 - T2;  // g*256 + c
            bb[i3] = b_nl[(size_t)(i3 >> 8) * 512 + (i3 & 255)] +
                     b_nl[(size_t)(i3 >> 8) * 512 + 256 + (i3 & 255)];
        } else {
            int i4 = idx - T1 - T2 - T3;
            out[i4] = b_out[i4 % 5];
        }
    }
}

// ---------------- emb -> bf16, pad 300 -> 320 ----------------
__global__ __launch_bounds__(256) void emb_to_bf16(
    const float* __restrict__ emb, unsigned short* __restrict__ embB)
{
    const int total = 131072 * 80;  // quads of 4
    for (int idx = blockIdx.x * 256 + threadIdx.x; idx < total;
         idx += gridDim.x * 256) {
        int r = idx / 80, q = idx % 80;
        ushort4v o;
        if (q < 75) {
            const float4 v = *(const float4*)(emb + (size_t)r * 300 + q * 4);
            o.x = f2bf(v.x); o.y = f2bf(v.y); o.z = f2bf(v.z); o.w = f2bf(v.w);
        } else {
            o.x = 0; o.y = 0; o.z = 0; o.w = 0;
        }
        *(ushort4v*)(embB + (size_t)r * 320 + q * 4) = o;
    }
}

extern "C" void kernel_launch(void* const* d_in, const int* in_sizes, int n_in,
                              void* d_out, int out_size, void* d_ws, size_t ws_size,
                              hipStream_t stream) {
    const float* emb    = (const float*)d_in[0];
    const float* W_leaf = (const float*)d_in[1];
    const float* b_leaf = (const float*)d_in[2];
    const float* W_nl   = (const float*)d_in[3];
    const float* b_nl   = (const float*)d_in[4];
    const float* W_out  = (const float*)d_in[5];
    const float* b_out  = (const float*)d_in[6];
    float* out = (float*)d_out;

    // workspace layout (bytes)
    char* ws = (char*)d_ws;
    unsigned short* embB   = (unsigned short*)(ws);              // 131072*320*2 = 83,886,080
    unsigned short* BleafT = (unsigned short*)(ws + 83886080);   // 768*320*2    =    491,520
    unsigned short* BlevT  = (unsigned short*)(ws + 84377600);   // 1280*512*2   =  1,310,720
    float*          bb     = (float*)(ws + 85688320);            // 5*256*4      =      5,120
    float*          cA     = (float*)(ws + 85693440);            // 131072*256*4 = 134,217,728
    unsigned short* hA     = (unsigned short*)(ws + 219911168);  // 131072*256*2 =  67,108,864
    float*          cB     = (float*)(ws + 287020032);           // 65536*256*4  =  67,108,864
    unsigned short* hB     = (unsigned short*)(ws + 354128896);  // 65536*256*2  =  33,554,432

    prep_weights<<<2048, 256, 0, stream>>>(W_leaf, W_nl, b_nl, b_out,
                                           BleafT, BlevT, bb, out);
    emb_to_bf16<<<2048, 256, 0, stream>>>(emb, embB);

    // leaf: M = 131072, K = 320, NG = 3 (+ fused logits, log2n=8, off=0)
    gemm_gates<3, 320, true><<<dim3(1024, 4), 256, 0, stream>>>(
        embB, BleafT, b_leaf, nullptr, cA, hA, W_out, out, 8, 0);

    const unsigned short* hp = hA;
    const float* cp = cA;
    int off = 256;
    for (int lev = 1; lev <= 8; ++lev) {
        int log2n = 8 - lev;
        int n = 1 << log2n;
        int M = 512 * n;
        float* cd = (lev & 1) ? cB : cA;
        unsigned short* hd = (lev & 1) ? hB : hA;
        gemm_gates<5, 512, false><<<dim3(M / 128, 4), 256, 0, stream>>>(
            hp, BlevT, bb, cp, cd, hd, W_out, out, log2n, off);
        cp = cd;
        hp = hd;
        off += n;
    }
}

// Round 6
// 502.295 us; speedup vs baseline: 11.2761x; 1.1046x over previous
//
#include <hip/hip_runtime.h>
#include <hip/hip_bf16.h>

// Binary tree LSTM, bf16-MFMA, 2-phase prefetch (T3-minimum) GEMMs.
// B=512, L=256, INP=300(pad 320), HID=256, NCLS=5.
//   prep:  pack weights to bf16 B^T panels, sum biases, fill out with b_out
//   emb:   fp32 emb -> bf16 embB (padded to 320)
//   leaf:  embB(131072x320) @ BleafT (tile 128x192, grid.y=4) -> gates+logits
//   level: h_prev (M x 512) @ BlevT (tile 128x160, grid.y=8)  -> gates+logits
// GEMM: BK=64, mfma_f32_16x16x32_bf16, double-buffered LDS,
// STAGE(next) issued before compute(cur), vmcnt(0)+raw s_barrier per K-step.
// global_load_lds(16B) pre-swizzled source, XOR-swizzled ds_read_b128.

#define HID 256

typedef __attribute__((ext_vector_type(8))) short short8;
typedef __attribute__((ext_vector_type(4))) float f32x4;
typedef __attribute__((ext_vector_type(4))) unsigned short ushort4v;

__device__ __forceinline__ float rcpf(float x) { return __builtin_amdgcn_rcpf(x); }
__device__ __forceinline__ float sigf(float x) { return rcpf(1.0f + __expf(-x)); }
__device__ __forceinline__ float tanhf_(float x) { return 2.0f * rcpf(1.0f + __expf(-2.0f * x)) - 1.0f; }
__device__ __forceinline__ unsigned short f2bf(float f) {
    __hip_bfloat16 b = __float2bfloat16(f);
    return *(unsigned short*)&b;
}
__device__ __forceinline__ void gload_lds16(const void* g, void* l) {
    __builtin_amdgcn_global_load_lds(
        (const __attribute__((address_space(1))) unsigned int*)g,
        (__attribute__((address_space(3))) unsigned int*)l, 16, 0, 0);
}

// ---------------- fused GEMM + gates + logits, 2-phase prefetch ----------
// A: (M x K) bf16 row-major. BT: (gridY*NG*CS x K) bf16 col-major-of-B,
// packed in CS-col-per-gate blocks. grid: (M/128, gridY). 4 waves (2Mx2N).
// CS: cols per gate per block (leaf 64, level 32). NF = CS/32 frags/gate/wave.
template <int NG, int CS, int K, bool LEAF>
__global__ __launch_bounds__(256, 2) void gemm_gates(
    const unsigned short* __restrict__ A,
    const unsigned short* __restrict__ BT,
    const float* __restrict__ bias,     // (NG x 256) effective bias
    const float* __restrict__ cprev,    // (M x 512) f32, level only
    float* __restrict__ cout,           // (M x 256) f32
    unsigned short* __restrict__ hout,  // (M x 256) bf16
    const float* __restrict__ W_out,    // (256, 5) f32
    float* __restrict__ out,            // logits, pre-filled with b_out
    int log2n, int off)
{
    constexpr int BN  = NG * CS;     // block cols
    constexpr int NK  = K / 64;
    constexpr int NF  = CS / 32;     // frags per gate per wave
    constexpr int NBW = BN / 32;     // B stage instrs per wave
    constexpr int BUF = (128 + BN) * 128;

    __shared__ char smem[2 * BUF];   // leaf 80KB, level 72KB

    const int t = threadIdx.x;
    const int lane = t & 63;
    const int w = t >> 6;
    const int wm = w >> 1, wn = w & 1;
    const int row0 = blockIdx.x * 128;
    const int cb = blockIdx.y;

    // ---- staging source offsets (pre-swizzled: slot ^= row&7) ----
    const int l3 = lane >> 3;
    const unsigned int swsrc = (unsigned int)(((lane & 7) ^ l3) * 16);
    unsigned int a_src[4];
    unsigned int b_src[NBW];
#pragma unroll
    for (int q = 0; q < 4; ++q)
        a_src[q] = (unsigned int)(row0 + (w * 4 + q) * 8 + l3) * (K * 2) + swsrc;
#pragma unroll
    for (int q = 0; q < NBW; ++q)
        b_src[q] = (unsigned int)(cb * BN + (w * NBW + q) * 8 + l3) * (K * 2) + swsrc;

    // ---- ds_read offsets ----
    const int swz0 = ((lane >> 4) ^ (lane & 7)) * 16;
    const int swz1 = (((lane >> 4) + 4) ^ (lane & 7)) * 16;
    const int aoff = (wm * 64 + (lane & 15)) * 128;
    const int boff = (wn * (CS / 2) + (lane & 15)) * 128;

    f32x4 acc[4][NG * NF] = {};

    auto STAGE = [&](int buf, int kt) {
        char* As = smem + buf * BUF;
        char* Bs = As + 128 * 128;
        const unsigned int k0b = (unsigned int)kt * 128;
#pragma unroll
        for (int q = 0; q < 4; ++q)
            gload_lds16((const char*)A + (size_t)(a_src[q] + k0b),
                        As + (w * 4 + q) * 1024);
#pragma unroll
        for (int q = 0; q < NBW; ++q)
            gload_lds16((const char*)BT + (size_t)(b_src[q] + k0b),
                        Bs + (w * NBW + q) * 1024);
    };

    // prologue
    STAGE(0, 0);
    asm volatile("s_waitcnt vmcnt(0)" ::: "memory");
    __builtin_amdgcn_s_barrier();

#pragma unroll
    for (int kt = 0; kt < NK; ++kt) {
        const int cur = kt & 1;
        if (kt + 1 < NK) STAGE(cur ^ 1, kt + 1);   // prefetch next tile
        const char* As = smem + cur * BUF;
        const char* Bs = As + 128 * 128;
#pragma unroll
        for (int ks = 0; ks < 2; ++ks) {
            const int sw = ks ? swz1 : swz0;
            short8 a[4];
#pragma unroll
            for (int mf = 0; mf < 4; ++mf)
                a[mf] = *(const short8*)(As + aoff + mf * 2048 + sw);
#pragma unroll
            for (int g = 0; g < NG; ++g)
#pragma unroll
                for (int fc = 0; fc < NF; ++fc) {
                    short8 b = *(const short8*)(Bs + g * (CS * 128) + boff +
                                                fc * 2048 + sw);
#pragma unroll
                    for (int mf = 0; mf < 4; ++mf)
                        acc[mf][g * NF + fc] = __builtin_amdgcn_mfma_f32_16x16x32_bf16(
                            a[mf], b, acc[mf][g * NF + fc], 0, 0, 0);
                }
        }
        asm volatile("s_waitcnt vmcnt(0)" ::: "memory");  // next tile landed
        __builtin_amdgcn_s_barrier();
    }

    // ---- epilogue: gates + h stash for logits ----
    float* hs = (float*)smem;                         // [128][CS+1]
    float* Ws = (float*)(smem + 128 * (CS + 1) * 4);  // [CS*5]
    for (int i = t; i < CS * 5; i += 256) Ws[i] = W_out[cb * CS * 5 + i];

#pragma unroll
    for (int mf = 0; mf < 4; ++mf) {
#pragma unroll
        for (int j = 0; j < 4; ++j) {
            const int rl = wm * 64 + mf * 16 + ((lane >> 4) << 2) + j;
            const int r = row0 + rl;
#pragma unroll
            for (int fc = 0; fc < NF; ++fc) {
                const int cl = wn * (CS / 2) + fc * 16 + (lane & 15);
                const int c = cb * CS + cl;
                float cv, hv;
                if constexpr (LEAF) {
                    float p0 = acc[mf][0 * NF + fc][j] + bias[c];          // i
                    float p1 = acc[mf][1 * NF + fc][j] + bias[256 + c];    // o
                    float p2 = acc[mf][2 * NF + fc][j] + bias[512 + c];    // u
                    cv = sigf(p0) * tanhf_(p2);
                    hv = sigf(p1) * sigf(cv);   // reference: o * sig(c)
                } else {
                    float p0 = acc[mf][0 * NF + fc][j] + bias[c];           // inp
                    float p1 = acc[mf][1 * NF + fc][j] + bias[256 + c];     // fol
                    float p2 = acc[mf][2 * NF + fc][j] + bias[512 + c];     // for
                    float p3 = acc[mf][3 * NF + fc][j] + bias[768 + c];     // out
                    float p4 = acc[mf][4 * NF + fc][j] + bias[1024 + c];    // upd
                    float lc = cprev[(size_t)r * 512 + c];
                    float rc = cprev[(size_t)r * 512 + 256 + c];
                    cv = sigf(p0) * tanhf_(p4) + sigf(p1) * lc + sigf(p2) * rc;
                    hv = sigf(p3) * tanhf_(cv);
                }
                cout[(size_t)r * 256 + c] = cv;
                hout[(size_t)r * 256 + c] = f2bf(hv);
                hs[rl * (CS + 1) + cl] = hv;
            }
        }
    }
    __syncthreads();

    // ---- fused logits: CS-col partial dot + atomicAdd ----
    const int nmask = (1 << log2n) - 1;
    for (int idx = t; idx < 128 * 5; idx += 256) {
        int rl = idx / 5, cls = idx - rl * 5;
        float s = 0.f;
#pragma unroll
        for (int c2 = 0; c2 < CS; ++c2)
            s = fmaf(hs[rl * (CS + 1) + c2], Ws[c2 * 5 + cls], s);
        int rg = row0 + rl;
        int b = rg >> log2n, jj = rg & nmask;
        atomicAdd(out + ((size_t)b * 511 + off + jj) * 5 + cls, s);
    }
}

// ---------------- weight prep + out init ----------------
__global__ __launch_bounds__(256) void prep_weights(
    const float* __restrict__ W_leaf, const float* __restrict__ W_nl,
    const float* __restrict__ b_nl, const float* __restrict__ b_out,
    unsigned short* __restrict__ BleafT, unsigned short* __restrict__ BlevT,
    float* __restrict__ bb, float* __restrict__ out)
{
    const int T1 = 768 * 320, T2 = 1280 * 512, T3 = 5 * 256, T4 = 261632 * 5;
    for (int idx = blockIdx.x * 256 + threadIdx.x; idx < T1 + T2 + T3 + T4;
         idx += gridDim.x * 256) {
        if (idx < T1) {
            // leaf: 64-col-per-gate blocks (gridY=4): colp = cb*192 + g*64 + cl
            int colp = idx / 320, k = idx % 320;
            int cbv = colp / 192, rem = colp % 192;
            int g = rem >> 6, cl = rem & 63;
            int c = cbv * 64 + cl;
            float v = (k < 300) ? W_leaf[((size_t)g * 300 + k) * 256 + c] : 0.0f;
            BleafT[(size_t)colp * 320 + k] = f2bf(v);
        } else if (idx < T1 + T2) {
            // level: 32-col-per-gate blocks (gridY=8): colp = cb*160 + g*32 + cl
            int i2 = idx - T1;
            int colp = i2 / 512, k = i2 % 512;
            int cb8 = colp / 160, rem = colp % 160;
            int g = rem >> 5, cl = rem & 31;
            int c = cb8 * 32 + cl;
            float v = W_nl[((size_t)(2 * g + (k >= 256)) * 256 + (k & 255)) * 256 + c];
            BlevT[(size_t)colp * 512 + k] = f2bf(v);
        } else if (idx < T1 + T2 + T3) {
            int i3 = idx - T1 - T2;  // g*256 + c
            bb[i3] = b_nl[(size_t)(i3 >> 8) * 512 + (i3 & 255)] +
                     b_nl[(size_t)(i3 >> 8) * 512 + 256 + (i3 & 255)];
        } else {
            int i4 = idx - T1 - T2 - T3;
            out[i4] = b_out[i4 % 5];
        }
    }
}

// ---------------- emb -> bf16, pad 300 -> 320 ----------------
__global__ __launch_bounds__(256) void emb_to_bf16(
    const float* __restrict__ emb, unsigned short* __restrict__ embB)
{
    const int total = 131072 * 80;  // quads of 4
    for (int idx = blockIdx.x * 256 + threadIdx.x; idx < total;
         idx += gridDim.x * 256) {
        int r = idx / 80, q = idx % 80;
        ushort4v o;
        if (q < 75) {
            const float4 v = *(const float4*)(emb + (size_t)r * 300 + q * 4);
            o.x = f2bf(v.x); o.y = f2bf(v.y); o.z = f2bf(v.z); o.w = f2bf(v.w);
        } else {
            o.x = 0; o.y = 0; o.z = 0; o.w = 0;
        }
        *(ushort4v*)(embB + (size_t)r * 320 + q * 4) = o;
    }
}

extern "C" void kernel_launch(void* const* d_in, const int* in_sizes, int n_in,
                              void* d_out, int out_size, void* d_ws, size_t ws_size,
                              hipStream_t stream) {
    const float* emb    = (const float*)d_in[0];
    const float* W_leaf = (const float*)d_in[1];
    const float* b_leaf = (const float*)d_in[2];
    const float* W_nl   = (const float*)d_in[3];
    const float* b_nl   = (const float*)d_in[4];
    const float* W_out  = (const float*)d_in[5];
    const float* b_out  = (const float*)d_in[6];
    float* out = (float*)d_out;

    // workspace layout (bytes)
    char* ws = (char*)d_ws;
    unsigned short* embB   = (unsigned short*)(ws);              // 131072*320*2 = 83,886,080
    unsigned short* BleafT = (unsigned short*)(ws + 83886080);   // 768*320*2    =    491,520
    unsigned short* BlevT  = (unsigned short*)(ws + 84377600);   // 1280*512*2   =  1,310,720
    float*          bb     = (float*)(ws + 85688320);            // 5*256*4      =      5,120
    float*          cA     = (float*)(ws + 85693440);            // 131072*256*4 = 134,217,728
    unsigned short* hA     = (unsigned short*)(ws + 219911168);  // 131072*256*2 =  67,108,864
    float*          cB     = (float*)(ws + 287020032);           // 65536*256*4  =  67,108,864
    unsigned short* hB     = (unsigned short*)(ws + 354128896);  // 65536*256*2  =  33,554,432

    prep_weights<<<2048, 256, 0, stream>>>(W_leaf, W_nl, b_nl, b_out,
                                           BleafT, BlevT, bb, out);
    emb_to_bf16<<<2048, 256, 0, stream>>>(emb, embB);

    // leaf: M = 131072, K = 320, NG = 3, CS = 64 (+ fused logits)
    gemm_gates<3, 64, 320, true><<<dim3(1024, 4), 256, 0, stream>>>(
        embB, BleafT, b_leaf, nullptr, cA, hA, W_out, out, 8, 0);

    const unsigned short* hp = hA;
    const float* cp = cA;
    int off = 256;
    for (int lev = 1; lev <= 8; ++lev) {
        int log2n = 8 - lev;
        int n = 1 << log2n;
        int M = 512 * n;
        float* cd = (lev & 1) ? cB : cA;
        unsigned short* hd = (lev & 1) ? hB : hA;
        gemm_gates<5, 32, 512, false><<<dim3(M / 128, 8), 256, 0, stream>>>(
            hp, BlevT, bb, cp, cd, hd, W_out, out, log2n, off);
        cp = cd;
        hp = hd;
        off += n;
    }
}